// Round 2
// baseline (1123.905 us; speedup 1.0000x reference)
//
#include <hip/hip_runtime.h>

// Problem constants: B=64, S=512, E=512, H=512, V=32000, T=2, L=1
// Output depends ONLY on batch sample 63 (lstm_out[-1] == last batch element).

typedef float f32x4 __attribute__((ext_vector_type(4)));
typedef unsigned long long u64;

#define NB 64   // persistent blocks for the recurrence (<= 256 CUs -> co-resident)

// LDS h-buffer swizzle: 32 chunks of 16 floats, padded to stride 20 words
// (80 B) -> float4 reads stay 16B-aligned, 16-way conflict -> 4-way.
// (measured last session: SQ_LDS_BANK_CONFLICT ~16 cy/step/block — negligible)
#define HIDX(e) ((((e) >> 4) * 20) + ((e) & 15))

// ---------------------------------------------------------------------------
// Kernel 1: xg[t][g] = sum_e emb[sent[63][t]][e] * W_ih[g][e] + b_ih[g]+b_hh[g]
// M=512 (t), N=2048 (g), K=512. Both operands K-major (NT GEMM). (unchanged)
// ---------------------------------------------------------------------------
__global__ __launch_bounds__(256) void xg_gemm_k(
    const int* __restrict__ sent, const float* __restrict__ emb,
    const float* __restrict__ W_ih, const float* __restrict__ b_ih,
    const float* __restrict__ b_hh, float* __restrict__ xg)
{
    __shared__ float As[16][65];   // [k][m]
    __shared__ float Bs[16][65];   // [k][n]
    __shared__ int aidx[64];
    const int tid = threadIdx.x;
    const int t0 = blockIdx.x * 64;
    const int n0 = blockIdx.y * 64;
    if (tid < 64) aidx[tid] = sent[63 * 512 + t0 + tid];
    __syncthreads();

    const int kk = tid & 15;   // k within tile
    const int mm = tid >> 4;   // 0..15
    const int tx = tid & 15, ty = tid >> 4;
    float acc[4][4] = {};

    for (int kb = 0; kb < 512; kb += 16) {
        #pragma unroll
        for (int j = 0; j < 4; j++) {
            int m = mm + j * 16;
            As[kk][m] = emb[(size_t)aidx[m] * 512 + kb + kk];
            Bs[kk][m] = W_ih[(size_t)(n0 + m) * 512 + kb + kk];
        }
        __syncthreads();
        #pragma unroll
        for (int k = 0; k < 16; k++) {
            float a[4], bv[4];
            #pragma unroll
            for (int i = 0; i < 4; i++) a[i] = As[k][ty * 4 + i];
            #pragma unroll
            for (int j = 0; j < 4; j++) bv[j] = Bs[k][tx * 4 + j];
            #pragma unroll
            for (int i = 0; i < 4; i++)
                #pragma unroll
                for (int j = 0; j < 4; j++)
                    acc[i][j] += a[i] * bv[j];
        }
        __syncthreads();
    }

    #pragma unroll
    for (int i = 0; i < 4; i++) {
        int t = t0 + ty * 4 + i;
        #pragma unroll
        for (int j = 0; j < 4; j++) {
            int col = n0 + tx * 4 + j;
            xg[(size_t)t * 2048 + col] = acc[i][j] + b_ih[col] + b_hh[col];
        }
    }
}

// ---------------------------------------------------------------------------
// Kernel 2: persistent batch-1 LSTM recurrence, 512 steps, 64 blocks x 256.
// Block b owns h-indices [b*8, b*8+8).
//
// Handoff (PROVEN protocol, unchanged): h values travel as tagged 64-bit
// slots  slot = (u64)(t+1)<<32 | float_bits(h_t), stored with relaxed
// agent-scope 8B atomic stores. Readers poll the slots themselves — the
// poll IS the data read. Two slot arrays ping-pong by step parity; the
// protocol is dependency-ordered race-free without fences.
//
// CHANGES vs 838us version (both intra-block only, protocol untouched):
//  * Row remap: thread (rg=tid>>5, cg=tid&31) owns the FOUR gate rows
//    {q*512 + b*8 + rg}, 16 cols each. After the 32-lane shuffle reduce,
//    lane cg==0 holds i,f,g,o of its j inline -> gate tail runs there.
//    Removes gacc LDS round-trip + 2nd barrier + wave-0 serialization.
//  * hbuf parity double-buffered -> exactly ONE __syncthreads per step.
//    (write of buf p at step t+2 is after barrier(t+1); every read of
//    buf p at step t is before barrier(t+1) -> race-free.)
//  * W_hh slice (64 floats/thread) pinned in VGPRs via empty "+v" asm —
//    previous build had VGPR_Count=60, i.e. weights were re-loaded from
//    L2 every step, chunk-serialized into the FMA phase.
// ---------------------------------------------------------------------------
__global__ __launch_bounds__(256, 1) void lstm_seq_k(
    const float* __restrict__ h0, const float* __restrict__ c0,
    const float* __restrict__ W_hh, const float* __restrict__ xg,
    float* __restrict__ hs,
    u64* __restrict__ sA, u64* __restrict__ sB)
{
    __shared__ float hb[2][648];   // 2 x (32 chunks * 20 words)

    const int tid = threadIdx.x;
    const int b = blockIdx.x;
    const int cg = tid & 31;   // column group: 16 cols each
    const int rg = tid >> 5;   // j within block: 8 h-indices

    // Gate rows for this thread's j: torch order i,f,g,o = q 0..3.
    int grow[4];
    #pragma unroll
    for (int r = 0; r < 4; ++r)
        grow[r] = r * 512 + b * 8 + rg;

    // Weight slice: 4 rows x 16 cols = 64 floats/thread, loaded ONCE.
    f32x4 w[4][4];
    #pragma unroll
    for (int r = 0; r < 4; ++r)
        #pragma unroll
        for (int cq = 0; cq < 4; ++cq)
            w[r][cq] = *(const f32x4*)&W_hh[(size_t)grow[r] * 512 + cg * 16 + cq * 4];

    // c state lives in the cg==0 lanes (loaded by all, used by cg==0).
    float creg = c0[63 * 512 + b * 8 + rg];

    for (int t = 0; t < 512; ++t) {
        // Pin weights in VGPRs: asm "may modify" them, so reloading from
        // global per-iteration is illegal for the compiler.
        #pragma unroll
        for (int r = 0; r < 4; ++r)
            asm volatile("" : "+v"(w[r][0]), "+v"(w[r][1]),
                              "+v"(w[r][2]), "+v"(w[r][3]));

        const int p = t & 1;

        // Prefetch xg for this step (independent of h -> overlaps the poll).
        float xgp[4];
        if (cg == 0) {
            #pragma unroll
            for (int r = 0; r < 4; ++r)
                xgp[r] = xg[(size_t)t * 2048 + grow[r]];
        }

        if (t == 0) {
            hb[p][HIDX(tid)]       = h0[63 * 512 + tid];
            hb[p][HIDX(tid + 256)] = h0[63 * 512 + tid + 256];
        } else {
            // Poll tagged slots of step t-1 (tag == t) in buffer (t-1)&1.
            u64* src = ((t - 1) & 1) ? sB : sA;
            u64* p0 = &src[tid];
            u64* p1 = &src[tid + 256];
            const unsigned expt = (unsigned)t;
            u64 v0, v1;
            for (;;) {
                v0 = __hip_atomic_load(p0, __ATOMIC_RELAXED, __HIP_MEMORY_SCOPE_AGENT);
                v1 = __hip_atomic_load(p1, __ATOMIC_RELAXED, __HIP_MEMORY_SCOPE_AGENT);
                if ((unsigned)(v0 >> 32) == expt &&
                    (unsigned)(v1 >> 32) == expt) break;
            }
            hb[p][HIDX(tid)]       = __uint_as_float((unsigned)v0);
            hb[p][HIDX(tid + 256)] = __uint_as_float((unsigned)v1);
        }
        __syncthreads();   // the ONLY barrier per step: hb[p] complete

        // 4 gate rows x 16 cols of FMA per thread.
        f32x4 hv[4];
        #pragma unroll
        for (int cq = 0; cq < 4; ++cq)
            hv[cq] = *(const f32x4*)&hb[p][cg * 20 + cq * 4];

        float acc[4];
        #pragma unroll
        for (int r = 0; r < 4; ++r) {
            float s = 0.f;
            #pragma unroll
            for (int cq = 0; cq < 4; ++cq) {
                s += w[r][cq].x * hv[cq].x;
                s += w[r][cq].y * hv[cq].y;
                s += w[r][cq].z * hv[cq].z;
                s += w[r][cq].w * hv[cq].w;
            }
            acc[r] = s;
        }

        // Reduce over the 32 column-group lanes (masks <=16 stay in-wave).
        #pragma unroll
        for (int r = 0; r < 4; ++r) {
            #pragma unroll
            for (int m = 16; m >= 1; m >>= 1)
                acc[r] += __shfl_xor(acc[r], m, 64);
        }

        // Gate tail inline on lane cg==0 of each row group (8 lanes,
        // spread over all 4 waves). Torch order: i, f, g, o.
        if (cg == 0) {
            float gi = acc[0] + xgp[0];
            float gf = acc[1] + xgp[1];
            float gc = acc[2] + xgp[2];
            float go = acc[3] + xgp[3];
            float ii = 1.f / (1.f + __expf(-gi));
            float ff = 1.f / (1.f + __expf(-gf));
            float cc = 1.f - 2.f / (__expf(2.f * gc) + 1.f);   // tanh
            float oo = 1.f / (1.f + __expf(-go));
            float cn = ff * creg + ii * cc;
            creg = cn;
            float th = 1.f - 2.f / (__expf(2.f * cn) + 1.f);   // tanh
            float hval = oo * th;

            // History for the final linear (plain store; kernel-boundary
            // release makes it visible to kernel 3).
            hs[(size_t)t * 512 + b * 8 + rg] = hval;

            // Tagged slot: one 8B relaxed agent atomic store.
            u64* dst = (t & 1) ? sB : sA;
            u64 pv = ((u64)(unsigned)(t + 1) << 32) |
                     (u64)__float_as_uint(hval);
            __hip_atomic_store(&dst[b * 8 + rg], pv,
                               __ATOMIC_RELAXED, __HIP_MEMORY_SCOPE_AGENT);
        }
        // NO fence, NO flag store, NO trailing barrier (hb double-buffered).
    }
}

// ---------------------------------------------------------------------------
// Kernel 3: out[s][u] = hs[s] . W_lin[u] + b_lin[u], S=512, T=2. (unchanged)
// ---------------------------------------------------------------------------
__global__ __launch_bounds__(256) void final_linear_k(
    const float* __restrict__ hs, const float* __restrict__ W_lin,
    const float* __restrict__ b_lin, float* __restrict__ out)
{
    const int tid = threadIdx.x;
    const int wave = tid >> 6;
    const int lane = tid & 63;
    const int s = blockIdx.x * 4 + wave;
    const float* h = hs + (size_t)s * 512;
    float a0 = 0.f, a1 = 0.f;
    #pragma unroll
    for (int k0 = 0; k0 < 512; k0 += 64) {
        float hv = h[k0 + lane];
        a0 += hv * W_lin[k0 + lane];
        a1 += hv * W_lin[512 + k0 + lane];
    }
    #pragma unroll
    for (int m = 32; m >= 1; m >>= 1) {
        a0 += __shfl_xor(a0, m, 64);
        a1 += __shfl_xor(a1, m, 64);
    }
    if (lane == 0) {
        out[s * 2]     = a0 + b_lin[0];
        out[s * 2 + 1] = a1 + b_lin[1];
    }
}

// ---------------------------------------------------------------------------
extern "C" void kernel_launch(void* const* d_in, const int* in_sizes, int n_in,
                              void* d_out, int out_size, void* d_ws, size_t ws_size,
                              hipStream_t stream)
{
    const int*   sent  = (const int*)d_in[0];     // [64,512] int32
    const float* h0    = (const float*)d_in[1];   // [1,64,512]
    const float* c0    = (const float*)d_in[2];   // [1,64,512]
    const float* emb   = (const float*)d_in[3];   // [32000,512]
    const float* W_ih  = (const float*)d_in[4];   // [2048,512]
    const float* W_hh  = (const float*)d_in[5];   // [2048,512]
    const float* b_ih  = (const float*)d_in[6];   // [2048]
    const float* b_hh  = (const float*)d_in[7];   // [2048]
    const float* W_lin = (const float*)d_in[8];   // [2,512]
    const float* b_lin = (const float*)d_in[9];   // [2]
    float* out = (float*)d_out;                   // [512,2]

    char* ws = (char*)d_ws;
    float* xg = (float*)ws;                                   // 4 MB: [512,2048]
    float* hs = (float*)(ws + 4 * 1024 * 1024);               // 1 MB: [512,512]
    u64* sA = (u64*)(ws + 5 * 1024 * 1024);                   // 4 KB
    u64* sB = (u64*)(ws + 5 * 1024 * 1024 + 4096);            // 4 KB

    // Clear slot tags (0 != any expected tag 1..512).
    hipMemsetAsync(sA, 0, 2 * 4096, stream);

    dim3 g1(8, 32);
    xg_gemm_k<<<g1, 256, 0, stream>>>(sent, emb, W_ih, b_ih, b_hh, xg);
    lstm_seq_k<<<NB, 256, 0, stream>>>(h0, c0, W_hh, xg, hs, sA, sB);
    final_linear_k<<<128, 256, 0, stream>>>(hs, W_lin, b_lin, out);
}